// Round 10
// baseline (302.034 us; speedup 1.0000x reference)
//
#include <hip/hip_runtime.h>
#include <hip/hip_fp16.h>

#define TPB 256
#define NBUCK 512          // node buckets of 256: bucket = id >> 8
#define SCAT_BLOCKS 256
#define SWEEP_BLOCKS 512
#define SEG_PER_BUCKET 4

// ---------------- kernels ----------------

__global__ void k_zero_i(int* p, int n) {
    int i = blockIdx.x * blockDim.x + threadIdx.x;
    if (i < n) p[i] = 0;
}

// both bucket histograms (dst-key and src-key) in one pass [proven R8]
__global__ void k_bhist2(const int* src, const int* dst, int* totD, int* totS, int E) {
    __shared__ int sh[1024];
    int t = threadIdx.x;                 // 512 threads
    sh[t] = 0; sh[t + 512] = 0;
    __syncthreads();
    for (int e = blockIdx.x * blockDim.x + t; e < E; e += gridDim.x * blockDim.x) {
        atomicAdd(&sh[dst[e] >> 8], 1);
        atomicAdd(&sh[512 + (src[e] >> 8)], 1);
    }
    __syncthreads();
    int c0 = sh[t], c1 = sh[512 + t];
    if (c0) atomicAdd(&totD[t], c0);
    if (c1) atomicAdd(&totS[t], c1);
}

// dual exclusive scan: blockIdx 0 -> D arrays, 1 -> S arrays [proven R8]
__global__ void k_bscan(const int* totD, const int* totS,
                        int* baseD, int* curD, int* baseS, int* curS) {
    const int* tot = blockIdx.x ? totS : totD;
    int* base = blockIdx.x ? baseS : baseD;
    int* cur  = blockIdx.x ? curS  : curD;
    __shared__ int sh[NBUCK];
    int t = threadIdx.x;
    int v = tot[t];
    sh[t] = v;
    __syncthreads();
    for (int off = 1; off < NBUCK; off <<= 1) {
        int a = (t >= off) ? sh[t - off] : 0;
        __syncthreads();
        sh[t] += a;
        __syncthreads();
    }
    int excl = sh[t] - v;
    base[t] = excl;
    cur[t] = excl;
    if (t == NBUCK - 1) base[NBUCK] = sh[t];
}

// partition by dst-bucket: packed = (dst&255)<<24 | src [proven R8]
__global__ void k_bscatD(const int* src, const int* dst, int* cursor,
                         int* packed, int E, int chunk) {
    __shared__ int shc[NBUCK], cur[NBUCK];
    int t = threadIdx.x;                 // 512 threads
    shc[t] = 0;
    __syncthreads();
    int e0 = blockIdx.x * chunk, e1 = min(E, e0 + chunk);
    for (int e = e0 + t; e < e1; e += 512) atomicAdd(&shc[dst[e] >> 8], 1);
    __syncthreads();
    int c = shc[t];
    if (c) cur[t] = atomicAdd(&cursor[t], c);
    __syncthreads();
    for (int e = e0 + t; e < e1; e += 512) {
        int d = dst[e];
        int off = atomicAdd(&cur[d >> 8], 1);
        packed[off] = ((d & 255) << 24) | src[e];
    }
}

// partition by src-bucket: packed = (src&255)<<24 | dst [proven R8]
__global__ void k_bscatS(const int* src, const int* dst, int* cursor,
                         int* packed, int E, int chunk) {
    __shared__ int shc[NBUCK], cur[NBUCK];
    int t = threadIdx.x;                 // 512 threads
    shc[t] = 0;
    __syncthreads();
    int e0 = blockIdx.x * chunk, e1 = min(E, e0 + chunk);
    for (int e = e0 + t; e < e1; e += 512) atomicAdd(&shc[src[e] >> 8], 1);
    __syncthreads();
    int c = shc[t];
    if (c) cur[t] = atomicAdd(&cursor[t], c);
    __syncthreads();
    for (int e = e0 + t; e < e1; e += 512) {
        int s = src[e];
        int off = atomicAdd(&cur[s >> 8], 1);
        packed[off] = ((s & 255) << 24) | dst[e];
    }
}

// per dst-bucket counting sort -> cnt, rowStart, dinv, u, csr [proven R5-R9]
__global__ void k_bucket_csr(const int* bucketBase, const int* packed, const float* x,
                             int* cnt, int* rowStart, float* dinv, float* u,
                             int* csr, int N) {
    __shared__ int c256[256];
    __shared__ int row256[256];
    __shared__ int cur256[256];
    const int b = blockIdx.x;
    const int t = threadIdx.x;
    const int nodeBase = b * 256;
    const int nodeCnt = min(N - nodeBase, 256);
    const int eb = bucketBase[b], ee = bucketBase[b + 1];

    c256[t] = 0;
    __syncthreads();
    for (int e = eb + t; e < ee; e += 256)
        atomicAdd(&c256[((unsigned)packed[e]) >> 24], 1);
    __syncthreads();

    int v = c256[t];
    row256[t] = v;
    __syncthreads();
    for (int off = 1; off < 256; off <<= 1) {
        int a = (t >= off) ? row256[t - off] : 0;
        __syncthreads();
        row256[t] += a;
        __syncthreads();
    }
    int excl = row256[t] - v;
    cur256[t] = excl;
    __syncthreads();

    if (t < nodeCnt) {
        int i = nodeBase + t;
        cnt[i] = v;
        rowStart[i] = eb + excl;
        float dv = rsqrtf(1.f + (float)v);
        dinv[i] = dv;
        u[i] = dv * x[i];
    }

    for (int e = eb + t; e < ee; e += 256) {
        int w = packed[e];
        int local = ((unsigned)w) >> 24;
        int s = w & 0x00FFFFFF;
        int off = atomicAdd(&cur256[local], 1);
        csr[eb + off] = s;
    }
}

// per-graph node counts via LDS (sorted batch -> narrow range per block)
__global__ void k_cntg(const int* batch, float* cntf, int N) {
    __shared__ int lc[512];
    __shared__ int sg0, sg1;
    const int t = threadIdx.x;           // 256
    const int i0 = blockIdx.x * 256;
    if (t == 0) { sg0 = batch[i0]; sg1 = batch[min(i0 + 255, N - 1)]; }
    lc[t] = 0; lc[t + 256] = 0;
    __syncthreads();
    int i = i0 + t;
    if (i < N) atomicAdd(&lc[batch[i] - sg0], 1);
    __syncthreads();
    for (int g = sg0 + t; g <= sg1; g += 256) {
        int c = lc[g - sg0];
        if (c) atomicAdd(&cntf[g], (float)c);
    }
}

// wg[i] = { w = dinv/cnt_g (bits), g }
__global__ void k_wg(const float* dinv, const int* batch, const float* cntf,
                     int2* wg, int N) {
    int i = blockIdx.x * blockDim.x + threadIdx.x;
    if (i >= N) return;
    int g = batch[i];
    float w = dinv[i] / fmaxf(cntf[g], 1.0f);
    wg[i] = make_int2(__float_as_int(w), g);
}

// M = W2 @ Wf  (64x16); bb = b2 @ Wf + bf  (16)
__global__ void k_Mbb(const float* W2, const float* Wf, const float* b2, const float* bf,
                      float* M, float* bb) {
    int t = threadIdx.x;           // single block of 1024
    int f = t >> 4, o = t & 15;
    float a = 0.f;
    for (int k = 0; k < 64; ++k) a = fmaf(W2[f * 64 + k], Wf[k * 16 + o], a);
    M[t] = a;
    if (t < 16) {
        float c = 0.f;
        for (int k = 0; k < 64; ++k) c = fmaf(b2[k], Wf[k * 16 + t], c);
        bb[t] = c + bf[t];
    }
}

// per node: s-gather over CSR (8-deep MLP) + layer-1 + fold; zd stored as half2 [proven R9]
__global__ void k_node(const int* rowStart, const int* cnt, const int* csr,
                       const float* u, const float* dinv,
                       const float* W1, const float* b1, const float* M,
                       __half2* zd, int N) {
    __shared__ float sW1[64], sb1[64], sM[1024];
    int t = threadIdx.x;
    if (t < 64) { sW1[t] = W1[t]; sb1[t] = b1[t]; }
    for (int j = t; j < 1024; j += blockDim.x) sM[j] = M[j];
    __syncthreads();
    int i = blockIdx.x * blockDim.x + t;
    if (i >= N) return;
    float dv = dinv[i];
    int rs = rowStart[i], dg = cnt[i];
    float a0 = u[i], a1 = 0.f, a2 = 0.f, a3 = 0.f;
    float a4 = 0.f, a5 = 0.f, a6 = 0.f, a7 = 0.f;
    int k = 0;
    for (; k + 8 <= dg; k += 8) {
        int s0 = csr[rs + k],     s1 = csr[rs + k + 1];
        int s2 = csr[rs + k + 2], s3 = csr[rs + k + 3];
        int s4 = csr[rs + k + 4], s5 = csr[rs + k + 5];
        int s6 = csr[rs + k + 6], s7 = csr[rs + k + 7];
        float v0 = u[s0], v1 = u[s1], v2 = u[s2], v3 = u[s3];
        float v4 = u[s4], v5 = u[s5], v6 = u[s6], v7 = u[s7];
        a0 += v0; a1 += v1; a2 += v2; a3 += v3;
        a4 += v4; a5 += v5; a6 += v6; a7 += v7;
    }
    for (; k < dg; ++k) a0 += u[csr[rs + k]];
    float s = dv * (((a0 + a1) + (a2 + a3)) + ((a4 + a5) + (a6 + a7)));
    float za[16];
#pragma unroll
    for (int o = 0; o < 16; ++o) za[o] = 0.f;
    for (int f = 0; f < 64; ++f) {
        float hf = fmaxf(fmaf(s, sW1[f], sb1[f]), 0.f);
#pragma unroll
        for (int o = 0; o < 16; ++o) za[o] = fmaf(hf, sM[f * 16 + o], za[o]);
    }
#pragma unroll
    for (int o = 0; o < 8; ++o)
        zd[i * 8 + o] = __floats2half2_rn(dv * za[2 * o], dv * za[2 * o + 1]);
}

// layer-2 + pooling sweep over src-bucketed edges.
// zd rows of the bucket preloaded to LDS; per edge: one merged 8B wg read,
// no dependent chain; accumulate into 32KB LDS gsum; one coalesced flush/block.
__global__ void k_sweep(const int* baseS, const int* packedS, const int2* wg,
                        const __half2* zd, float* gsum, int NB, int N) {
    __shared__ float lg[8192];           // 32 KB: private per-graph accumulator
    __shared__ __half2 zdl[2048];        // 8 KB: this bucket's zd rows
    const int t = threadIdx.x;           // 512
    for (int q = t; q < 8192; q += 512) lg[q] = 0.f;
    const int j = t & 7;
    const int nseg = NB * SEG_PER_BUCKET;
    for (int seg = blockIdx.x; seg < nseg; seg += gridDim.x) {
        const int bk = seg / SEG_PER_BUCKET, sub = seg - bk * SEG_PER_BUCKET;
        const int srcBase = bk << 8;
        __syncthreads();                 // zdl re-use fence (also covers lg zeroing)
        for (int q = t; q < 2048; q += 512) {
            int i = srcBase + (q >> 3);
            zdl[q] = (i < N) ? zd[(size_t)i * 8 + (q & 7)] : __floats2half2_rn(0.f, 0.f);
        }
        __syncthreads();
        if (sub == 0) {                  // self-loop terms, once per bucket
            for (int n = t >> 3; n < 256; n += 64) {
                int i = srcBase + n;
                if (i < N) {
                    int2 wgv = wg[i];
                    float wv = __int_as_float(wgv.x);
                    float2 f = __half22float2(zdl[(n << 3) + j]);
                    atomicAdd(&lg[(wgv.y << 4) + 2 * j],     wv * f.x);
                    atomicAdd(&lg[(wgv.y << 4) + 2 * j + 1], wv * f.y);
                }
            }
        }
        const int e0 = baseS[bk], e1 = baseS[bk + 1];
        const int per = (e1 - e0 + SEG_PER_BUCKET - 1) / SEG_PER_BUCKET;
        const int es = e0 + sub * per;
        const int ee = min(e1, es + per);
        int p = es + (t >> 3);
        for (; p + 64 < ee; p += 128) {  // 2-deep independent loads
            int pk0 = packedS[p], pk1 = packedS[p + 64];
            int2 w0 = wg[pk0 & 0xFFFFFF];
            int2 w1 = wg[pk1 & 0xFFFFFF];
            float2 f0 = __half22float2(zdl[((((unsigned)pk0) >> 24) << 3) + j]);
            float2 f1 = __half22float2(zdl[((((unsigned)pk1) >> 24) << 3) + j]);
            float wv0 = __int_as_float(w0.x), wv1 = __int_as_float(w1.x);
            atomicAdd(&lg[(w0.y << 4) + 2 * j],     wv0 * f0.x);
            atomicAdd(&lg[(w0.y << 4) + 2 * j + 1], wv0 * f0.y);
            atomicAdd(&lg[(w1.y << 4) + 2 * j],     wv1 * f1.x);
            atomicAdd(&lg[(w1.y << 4) + 2 * j + 1], wv1 * f1.y);
        }
        for (; p < ee; p += 64) {
            int pk = packedS[p];
            int2 w0 = wg[pk & 0xFFFFFF];
            float2 f0 = __half22float2(zdl[((((unsigned)pk) >> 24) << 3) + j]);
            float wv0 = __int_as_float(w0.x);
            atomicAdd(&lg[(w0.y << 4) + 2 * j],     wv0 * f0.x);
            atomicAdd(&lg[(w0.y << 4) + 2 * j + 1], wv0 * f0.y);
        }
    }
    __syncthreads();
    for (int q = t; q < 8192; q += 512) {
        float v = lg[q];
        if (v != 0.f) atomicAdd(&gsum[q], v);   // coalesced flush
    }
}

__global__ void k_final(const float* gsum, const float* bb, float* out, int n16) {
    int t = blockIdx.x * blockDim.x + threadIdx.x;
    if (t >= n16) return;
    out[t] = gsum[t] + bb[t & 15];
}

// ---------------- launch ----------------

static inline int cdiv(int a, int b) { return (a + b - 1) / b; }

extern "C" void kernel_launch(void* const* d_in, const int* in_sizes, int n_in,
                              void* d_out, int out_size, void* d_ws, size_t ws_size,
                              hipStream_t stream) {
    const float* x   = (const float*)d_in[0];
    const int*   ei  = (const int*)d_in[1];   // [2,E]: src then dst
    const int*   bat = (const int*)d_in[2];
    const float* W1  = (const float*)d_in[4];
    const float* b1  = (const float*)d_in[5];
    const float* W2  = (const float*)d_in[6];
    const float* b2  = (const float*)d_in[7];
    const float* Wf  = (const float*)d_in[8];
    const float* bf  = (const float*)d_in[9];
    float* out = (float*)d_out;

    const int N = in_sizes[0];        // Fin = 1
    const int E = in_sizes[1] / 2;
    const int G = out_size / 16;
    const int NB = cdiv(N, 256);

    const int* src = ei;
    const int* dst = ei + E;

    // workspace (4B elems):
    //  region0 [E]: packedD, then zd (half2, 8N = 32N B <= 4E B) overlays it
    //  region1 [E]: csr, then packedS overlays it (csr dead after k_node)
    char* w = (char*)d_ws;
    int*     packedD = (int*)w;
    __half2* zd      = (__half2*)w;     w += (size_t)E * 4;
    int*     csr     = (int*)w;
    int*     packedS = (int*)w;         w += (size_t)E * 4;
    int*   cnt      = (int*)w;          w += (size_t)N * 4;
    int*   rowStart = (int*)w;          w += (size_t)N * 4;
    float* dinv     = (float*)w;        w += (size_t)N * 4;
    float* u        = (float*)w;        w += (size_t)N * 4;
    int2*  wg       = (int2*)w;         w += (size_t)2 * N * 4;   // 8B aligned (E,N even)
    int*   baseD    = (int*)w;          w += (NBUCK + 1) * 4;
    int*   curD     = (int*)w;          w += NBUCK * 4;
    int*   baseS    = (int*)w;          w += (NBUCK + 1) * 4;
    int*   curS     = (int*)w;          w += (NBUCK + 2) * 4;     // pad to even
    // contiguous zero region: totD | totS | gsum | cntf
    int*   totD     = (int*)w;          w += NBUCK * 4;
    int*   totS     = (int*)w;          w += NBUCK * 4;
    float* gsum     = (float*)w;        w += (size_t)16 * G * 4;
    float* cntf     = (float*)w;        w += (size_t)G * 4;
    float* M        = (float*)w;        w += 1024 * 4;
    float* bb       = (float*)w;

    const int nzero = NBUCK + NBUCK + 16 * G + G;
    const int chunk = cdiv(E, SCAT_BLOCKS);

    // 0) zero counters/accumulators
    k_zero_i<<<cdiv(nzero, 256), 256, 0, stream>>>(totD, nzero);

    // 1-2) dual histogram + dual scan
    k_bhist2<<<256, 512, 0, stream>>>(src, dst, totD, totS, E);
    k_bscan<<<2, NBUCK, 0, stream>>>(totD, totS, baseD, curD, baseS, curS);

    // 3) dst-partition -> packedD; 4) per-bucket CSR + dinv/u
    k_bscatD<<<SCAT_BLOCKS, 512, 0, stream>>>(src, dst, curD, packedD, E, chunk);
    k_bucket_csr<<<NB, 256, 0, stream>>>(baseD, packedD, x, cnt, rowStart, dinv, u, csr, N);

    // 5) per-graph counts; 6) per-node {w,g}
    k_cntg<<<NB, 256, 0, stream>>>(bat, cntf, N);
    k_wg<<<cdiv(N, 256), 256, 0, stream>>>(dinv, bat, cntf, wg, N);

    // 7) folded weights
    k_Mbb<<<1, 1024, 0, stream>>>(W2, Wf, b2, bf, M, bb);

    // 8) layer-1 gather + MLP -> zd (overlays packedD, dead after step 4)
    k_node<<<cdiv(N, TPB), TPB, 0, stream>>>(rowStart, cnt, csr, u, dinv, W1, b1, M, zd, N);

    // 9) src-partition -> packedS (overlays csr, dead after step 8)
    k_bscatS<<<SCAT_BLOCKS, 512, 0, stream>>>(src, dst, curS, packedS, E, chunk);

    // 10) layer-2 + pooling sweep
    k_sweep<<<SWEEP_BLOCKS, 512, 0, stream>>>(baseS, packedS, wg, zd, gsum, NB, N);

    // 11) finalize
    k_final<<<cdiv(G * 16, 256), 256, 0, stream>>>(gsum, bb, out, G * 16);
}

// Round 11
// 136.907 us; speedup vs baseline: 2.2061x; 2.2061x over previous
//
#include <hip/hip_runtime.h>
#include <hip/hip_fp16.h>

#define TPB 256
#define NBUCK 512          // buckets of 256 nodes: bucket = dst >> 8
#define A2_BLOCKS 400

// ---------------- kernels ----------------

__global__ void k_zero_i(int* p, int n) {
    int i = blockIdx.x * blockDim.x + threadIdx.x;
    if (i < n) p[i] = 0;
}

__global__ void k_zero_f(float* p, int n) {
    int i = blockIdx.x * blockDim.x + threadIdx.x;
    if (i < n) p[i] = 0.f;
}

// A0: bucket histogram, LDS-privatized; ~131K global atomics total
__global__ void k_bhistA(const int* dst, int* bucketTot, int E) {
    __shared__ int sh[NBUCK];
    int t = threadIdx.x;
    sh[t] = 0; sh[t + 256] = 0;
    __syncthreads();
    for (int e = blockIdx.x * blockDim.x + t; e < E; e += gridDim.x * blockDim.x)
        atomicAdd(&sh[dst[e] >> 8], 1);
    __syncthreads();
    int c0 = sh[t], c1 = sh[t + 256];
    if (c0) atomicAdd(&bucketTot[t], c0);
    if (c1) atomicAdd(&bucketTot[t + 256], c1);
}

// A1: exclusive scan of 512 bucket totals -> base; init cursor
__global__ void k_bscan(const int* tot, int* base, int* cursor) {
    __shared__ int sh[NBUCK];
    int t = threadIdx.x;
    int v = tot[t];
    sh[t] = v;
    __syncthreads();
    for (int off = 1; off < NBUCK; off <<= 1) {
        int a = (t >= off) ? sh[t - off] : 0;
        __syncthreads();
        sh[t] += a;
        __syncthreads();
    }
    int excl = sh[t] - v;
    base[t] = excl;
    cursor[t] = excl;
    if (t == NBUCK - 1) base[NBUCK] = sh[t];
}

// A2: partition edges into bucket-contiguous regions as packed words
// word = (dst & 255) << 24 | src
__global__ void k_bscatter(const int* src, const int* dst, int* bucketCursor,
                           int* packed, int E, int chunk) {
    __shared__ int shc[NBUCK];
    __shared__ int cur[NBUCK];
    int t = threadIdx.x;
    shc[t] = 0; shc[t + 256] = 0;
    __syncthreads();
    int e0 = blockIdx.x * chunk;
    int e1 = min(E, e0 + chunk);
    for (int e = e0 + t; e < e1; e += 256)
        atomicAdd(&shc[dst[e] >> 8], 1);
    __syncthreads();
    int c0 = shc[t], c1 = shc[t + 256];
    if (c0) cur[t] = atomicAdd(&bucketCursor[t], c0);
    if (c1) cur[t + 256] = atomicAdd(&bucketCursor[t + 256], c1);
    __syncthreads();
    for (int e = e0 + t; e < e1; e += 256) {
        int d = dst[e];
        int b = d >> 8;
        int off = atomicAdd(&cur[b], 1);
        packed[off] = ((d & 255) << 24) | src[e];
    }
}

// B: per-bucket counting sort -> cnt, rowStart, dinv, u, csr (one wg per bucket)
__global__ void k_bucket_csr(const int* bucketBase, const int* packed, const float* x,
                             int* cnt, int* rowStart, float* dinv, float* u,
                             int* csr, int N) {
    __shared__ int c256[256];
    __shared__ int row256[256];
    __shared__ int cur256[256];
    const int b = blockIdx.x;
    const int t = threadIdx.x;
    const int nodeBase = b * 256;
    const int nodeCnt = min(N - nodeBase, 256);
    const int eb = bucketBase[b], ee = bucketBase[b + 1];

    c256[t] = 0;
    __syncthreads();
    for (int e = eb + t; e < ee; e += 256)
        atomicAdd(&c256[((unsigned)packed[e]) >> 24], 1);
    __syncthreads();

    int v = c256[t];
    row256[t] = v;
    __syncthreads();
    for (int off = 1; off < 256; off <<= 1) {
        int a = (t >= off) ? row256[t - off] : 0;
        __syncthreads();
        row256[t] += a;
        __syncthreads();
    }
    int excl = row256[t] - v;
    cur256[t] = excl;
    __syncthreads();

    if (t < nodeCnt) {
        int i = nodeBase + t;
        cnt[i] = v;
        rowStart[i] = eb + excl;
        float dv = rsqrtf(1.f + (float)v);
        dinv[i] = dv;
        u[i] = dv * x[i];
    }

    for (int e = eb + t; e < ee; e += 256) {
        int w = packed[e];
        int local = ((unsigned)w) >> 24;
        int s = w & 0x00FFFFFF;
        int off = atomicAdd(&cur256[local], 1);
        csr[eb + off] = s;
    }
}

// M = W2 @ Wf  (64x16); bb = b2 @ Wf + bf  (16)
__global__ void k_Mbb(const float* W2, const float* Wf, const float* b2, const float* bf,
                      float* M, float* bb) {
    int t = threadIdx.x;           // single block of 1024
    int f = t >> 4, o = t & 15;
    float a = 0.f;
    for (int k = 0; k < 64; ++k) a = fmaf(W2[f * 64 + k], Wf[k * 16 + o], a);
    M[t] = a;
    if (t < 16) {
        float c = 0.f;
        for (int k = 0; k < 64; ++k) c = fmaf(b2[k], Wf[k * 16 + t], c);
        bb[t] = c + bf[t];
    }
}

// per node: masked 16-deep s-gather over CSR + layer-1 + fold; zd stored as half2.
// All loads of a 16-chunk are independent (clamped index + predicated add) --
// no serial-dependent tail.
__global__ void k_node(const int* rowStart, const int* cnt, const int* csr,
                       const float* u, const float* dinv,
                       const float* W1, const float* b1, const float* M,
                       __half2* zd, int N) {
    __shared__ float sW1[64], sb1[64], sM[1024];
    int t = threadIdx.x;
    if (t < 64) { sW1[t] = W1[t]; sb1[t] = b1[t]; }
    for (int j = t; j < 1024; j += blockDim.x) sM[j] = M[j];
    __syncthreads();
    int i = blockIdx.x * blockDim.x + t;
    if (i >= N) return;
    float dv = dinv[i];
    int rs = rowStart[i], dg = cnt[i];
    int dgm1 = dg - 1;
    float acc[8];
    acc[0] = u[i];   // self-loop seed
#pragma unroll
    for (int l = 1; l < 8; ++l) acc[l] = 0.f;
    for (int k = 0; k < dg; k += 16) {
        int sidx[16];
#pragma unroll
        for (int l = 0; l < 16; ++l) sidx[l] = csr[rs + min(k + l, dgm1)];
        float vv[16];
#pragma unroll
        for (int l = 0; l < 16; ++l) vv[l] = u[sidx[l]];
#pragma unroll
        for (int l = 0; l < 16; ++l) acc[l & 7] += (k + l < dg) ? vv[l] : 0.f;
    }
    float s = dv * (((acc[0] + acc[1]) + (acc[2] + acc[3])) +
                    ((acc[4] + acc[5]) + (acc[6] + acc[7])));
    float za[16];
#pragma unroll
    for (int o = 0; o < 16; ++o) za[o] = 0.f;
    for (int f = 0; f < 64; ++f) {
        float hf = fmaxf(fmaf(s, sW1[f], sb1[f]), 0.f);
#pragma unroll
        for (int o = 0; o < 16; ++o) za[o] = fmaf(hf, sM[f * 16 + o], za[o]);
    }
#pragma unroll
    for (int o = 0; o < 8; ++o)
        zd[i * 8 + o] = __floats2half2_rn(dv * za[2 * o], dv * za[2 * o + 1]);
}

// layer-2 gather + mean-pool, fused. Block = 32 nodes x 8 lanes; each lane owns
// an output PAIR (one half2 per edge). Masked 16-deep batches: every row of
// dg<=16 is ONE parallel load round, no serial tail.
__global__ void k_gather_pool(const int* batch, const int* rowStart, const int* cnt,
                              const int* csr, const __half2* zd, const float* dinv,
                              float* gsum, float* cntf, int N) {
    const int t = threadIdx.x, j = t & 7, row = t >> 3;
    const int i0 = blockIdx.x * 32;
    const int i = i0 + row;
    const bool valid = i < N;
    float vx = 0.f, vy = 0.f;
    int g = 0;
    if (valid) {
        g = batch[i];
        int rs = rowStart[i], dg = cnt[i];
        int dgm1 = dg - 1;
        float2 a[8];
        a[0] = __half22float2(zd[i * 8 + j]);   // self-loop seed
#pragma unroll
        for (int l = 1; l < 8; ++l) a[l] = make_float2(0.f, 0.f);
        for (int k = 0; k < dg; k += 16) {
            int sidx[16];
#pragma unroll
            for (int l = 0; l < 16; ++l) sidx[l] = csr[rs + min(k + l, dgm1)];
            float2 h[16];
#pragma unroll
            for (int l = 0; l < 16; ++l) h[l] = __half22float2(zd[sidx[l] * 8 + j]);
#pragma unroll
            for (int l = 0; l < 16; ++l) {
                bool m = (k + l) < dg;
                a[l & 7].x += m ? h[l].x : 0.f;
                a[l & 7].y += m ? h[l].y : 0.f;
            }
        }
        float dvv = dinv[i];
        vx = dvv * (((a[0].x + a[1].x) + (a[2].x + a[3].x)) +
                    ((a[4].x + a[5].x) + (a[6].x + a[7].x)));
        vy = dvv * (((a[0].y + a[1].y) + (a[2].y + a[3].y)) +
                    ((a[4].y + a[5].y) + (a[6].y + a[7].y)));
    }

    __shared__ int s_g0, s_g1, s_nvalid;
    if (t == 0) {
        s_g0 = batch[i0];
        int ilast = min(i0 + 31, N - 1);
        s_g1 = batch[ilast];
        s_nvalid = min(N - i0, 32);
    }
    __shared__ float red[32][17];
    red[row][2 * j]     = vx;
    red[row][2 * j + 1] = vy;
    __syncthreads();

    if (s_g0 == s_g1) {
        if (t < 16) {
            float a = 0.f;
#pragma unroll
            for (int r = 0; r < 32; ++r) a += red[r][t];
            atomicAdd(&gsum[s_g0 * 16 + t], a);
            if (t == 0) atomicAdd(&cntf[s_g0], (float)s_nvalid);
        }
    } else {
        if (valid) {
            atomicAdd(&gsum[g * 16 + 2 * j],     vx);
            atomicAdd(&gsum[g * 16 + 2 * j + 1], vy);
            if (j == 0) atomicAdd(&cntf[g], 1.0f);
        }
    }
}

__global__ void k_final(const float* gsum, const float* cntf, const float* bb,
                        float* out, int G) {
    int t = blockIdx.x * blockDim.x + threadIdx.x;
    int g = t >> 4, o = t & 15;
    if (g >= G) return;
    out[t] = gsum[t] / fmaxf(cntf[g], 1.0f) + bb[o];
}

// ---------------- launch ----------------

static inline int cdiv(int a, int b) { return (a + b - 1) / b; }

extern "C" void kernel_launch(void* const* d_in, const int* in_sizes, int n_in,
                              void* d_out, int out_size, void* d_ws, size_t ws_size,
                              hipStream_t stream) {
    const float* x   = (const float*)d_in[0];
    const int*   ei  = (const int*)d_in[1];   // [2,E]: src then dst
    const int*   bat = (const int*)d_in[2];
    const float* W1  = (const float*)d_in[4];
    const float* b1  = (const float*)d_in[5];
    const float* W2  = (const float*)d_in[6];
    const float* b2  = (const float*)d_in[7];
    const float* Wf  = (const float*)d_in[8];
    const float* bf  = (const float*)d_in[9];
    float* out = (float*)d_out;

    const int N = in_sizes[0];        // Fin = 1
    const int E = in_sizes[1] / 2;
    const int G = out_size / 16;

    const int* src = ei;
    const int* dst = ei + E;

    // workspace layout. zd (half2, 32B/node) overlays packed (dead after k_bucket_csr).
    char* w = (char*)d_ws;
    int*   bucketTot    = (int*)w;      w += NBUCK * 4;
    int*   bucketBase   = (int*)w;      w += (NBUCK + 1) * 4;
    int*   bucketCursor = (int*)w;      w += NBUCK * 4 + 256;  // pad
    int*   packed       = (int*)w;                 // [E] ints
    __half2* zd         = (__half2*)packed;        // [8N] half2 overlay (32N B <= 4E B)
    w += (size_t)(E > 8 * N ? E : 8 * N) * 4;
    int*   csr      = (int*)w;          w += (size_t)E * 4;
    int*   cnt      = (int*)w;          w += (size_t)N * 4;
    int*   rowStart = (int*)w;          w += (size_t)N * 4;
    float* dinv     = (float*)w;        w += (size_t)N * 4;
    float* u        = (float*)w;        w += (size_t)N * 4;
    float* gsum     = (float*)w;        w += (size_t)16 * G * 4;
    float* cntf     = (float*)w;        w += (size_t)G * 4;
    float* M        = (float*)w;        w += 1024 * 4;
    float* bb       = (float*)w;

    const int chunk = cdiv(E, A2_BLOCKS);

    // CSR build: bucketed counting sort (atomics mostly in LDS)
    k_zero_i<<<1, NBUCK, 0, stream>>>(bucketTot, NBUCK);
    k_bhistA<<<256, 256, 0, stream>>>(dst, bucketTot, E);
    k_bscan<<<1, NBUCK, 0, stream>>>(bucketTot, bucketBase, bucketCursor);
    k_bscatter<<<A2_BLOCKS, 256, 0, stream>>>(src, dst, bucketCursor, packed, E, chunk);
    k_bucket_csr<<<cdiv(N, 256), 256, 0, stream>>>(bucketBase, packed, x,
                                                   cnt, rowStart, dinv, u, csr, N);

    // folded weights
    k_Mbb<<<1, 1024, 0, stream>>>(W2, Wf, b2, bf, M, bb);

    // layer-1 gather + transform -> zd (half2; overlays packed, now dead)
    k_node<<<cdiv(N, TPB), TPB, 0, stream>>>(rowStart, cnt, csr, u, dinv, W1, b1, M, zd, N);

    // layer-2 gather + pool
    k_zero_f<<<cdiv(16 * G + G, TPB), TPB, 0, stream>>>(gsum, 16 * G + G);
    k_gather_pool<<<cdiv(N, 32), 256, 0, stream>>>(bat, rowStart, cnt, csr, zd, dinv, gsum, cntf, N);

    // finalize
    k_final<<<cdiv(G * 16, TPB), TPB, 0, stream>>>(gsum, cntf, bb, out, G);
}